// Round 9
// baseline (214.178 us; speedup 1.0000x reference)
//
#include <hip/hip_runtime.h>

typedef unsigned short u16;
typedef __attribute__((ext_vector_type(8))) short short8;
typedef __attribute__((ext_vector_type(4))) float floatx4;

#define NB 8192        // rows
#define DK 1024        // D_IN
#define DN 1024        // D_OUT
#define NE 16          // experts
#define TM 128
#define TN 128
#define BK 64
#define MAX_TILES 80   // sum ceil(cnt_e/128) <= 64 + 16
#define GTHR 4e-3f     // split-bf16 gate error < 1e-4 worst-case; 40x margin

#define GATE_BLOCKS 512
#define TRANS_BLOCKS 2048  // 8192 wave-tasks: (e, kgrp of 32, ngrp of 64)

__device__ __forceinline__ u16 f2bf(float f) {
    union { float f; unsigned int u; } v; v.f = f;
    unsigned int u = v.u;
    return (u16)((u + 0x7fffu + ((u >> 16) & 1u)) >> 16);
}

__device__ __forceinline__ float bf2f(u16 h) {
    union { unsigned int u; float f; } v; v.u = ((unsigned int)h) << 16;
    return v.f;
}

__device__ __forceinline__ void gld16(const void* g, void* l) {
    __builtin_amdgcn_global_load_lds(
        (const __attribute__((address_space(1))) unsigned int*)g,
        (__attribute__((address_space(3))) unsigned int*)l, 16, 0, 0);
}

// ---------------- K1: fused [direct-frag split-bf16 MFMA gate + x->bf16] | [streaming We transpose] ----------------
// blocks 0..511: gate, 16 rows each, no staging LDS (frags loaded per-lane from global).
//   cc-loop unroll 2: two k-chunks of loads in flight per wave (VGPR headroom 32->64 at
//   8 blocks/CU) - probes latency-bound vs fabric-bound for the 63.5us invariance.
// blocks 512..2559: We fp32 [E][K][N] -> bf16 [E][N][K]; full-64B-line-per-lane writes.
__global__ __launch_bounds__(256, 8) void k_prep(const float* __restrict__ x,
                                                 const float* __restrict__ Wg,
                                                 const float* __restrict__ bg,
                                                 const float* __restrict__ We,
                                                 u16* __restrict__ xb,
                                                 u16* __restrict__ WeT,
                                                 int* __restrict__ cnt,
                                                 int* __restrict__ bucket,
                                                 int* __restrict__ fixcnt,
                                                 int* __restrict__ fixlist) {
    __shared__ float gred[4][16 * 17];   // 4.3 KB: cross-wave gate reduction only

    const int tid = threadIdx.x;

    if (blockIdx.x < GATE_BLOCKS) {
        const int lane = tid & 63;
        const int w = tid >> 6;
        const int lr = lane & 15, q = lane >> 4;
        const int R0 = blockIdx.x * 16;
        const size_t xrow = (size_t)(R0 + lr) * DK;

        floatx4 acc = (floatx4)0.0f;

        // wave w covers k in [w*256, w*256+256); per lane: row lr, k-subchunks q*8
        #pragma unroll 2
        for (int cc = 0; cc < 4; ++cc) {
            const int kc = w * 256 + cc * 64;
            #pragma unroll
            for (int kwin = 0; kwin < 2; ++kwin) {
                const int kb = kc + kwin * 32 + q * 8;
                // A fragment: x[R0+lr][kb..kb+8), split hi/lo bf16; emit hi to xb
                const float* gp = &x[xrow + kb];
                float4 v0 = *(const float4*)gp;
                float4 v1 = *(const float4*)(gp + 4);
                float av[8] = { v0.x, v0.y, v0.z, v0.w, v1.x, v1.y, v1.z, v1.w };
                u16 ah[8], al[8];
                #pragma unroll
                for (int j = 0; j < 8; ++j) {
                    ah[j] = f2bf(av[j]);
                    al[j] = f2bf(av[j] - bf2f(ah[j]));
                }
                *(short8*)&xb[xrow + kb] = *(const short8*)ah;
                // B fragment: Wg[kb+j][lr] (col = expert lr), split hi/lo
                float wv[8];
                #pragma unroll
                for (int j = 0; j < 8; ++j)
                    wv[j] = Wg[(size_t)(kb + j) * NE + lr];
                u16 bh[8], bl[8];
                #pragma unroll
                for (int j = 0; j < 8; ++j) {
                    bh[j] = f2bf(wv[j]);
                    bl[j] = f2bf(wv[j] - bf2f(bh[j]));
                }
                const short8 ahv = *(const short8*)ah;
                const short8 alv = *(const short8*)al;
                const short8 bhv = *(const short8*)bh;
                const short8 blv = *(const short8*)bl;
                acc = __builtin_amdgcn_mfma_f32_16x16x32_bf16(ahv, bhv, acc, 0, 0, 0);
                acc = __builtin_amdgcn_mfma_f32_16x16x32_bf16(ahv, blv, acc, 0, 0, 0);
                acc = __builtin_amdgcn_mfma_f32_16x16x32_bf16(alv, bhv, acc, 0, 0, 0);
            }
        }

        #pragma unroll
        for (int rr = 0; rr < 4; ++rr)
            gred[w][(q * 4 + rr) * 17 + lr] = acc[rr];
        __syncthreads();

        if (tid < 16) {
            int row = R0 + tid;
            float g[16];
            #pragma unroll
            for (int e = 0; e < 16; ++e)
                g[e] = gred[0][tid * 17 + e] + gred[1][tid * 17 + e]
                     + gred[2][tid * 17 + e] + gred[3][tid * 17 + e] + bg[e];
            float best = g[0], second = -1e30f; int bi = 0;
            #pragma unroll
            for (int e = 1; e < 16; ++e) {
                if (g[e] > best) { second = best; best = g[e]; bi = e; }
                else if (g[e] > second) second = g[e];
            }
            if (best - second >= GTHR) {
                int pos = atomicAdd(&cnt[bi], 1);
                bucket[bi * NB + pos] = row;
            } else {
                int f = atomicAdd(fixcnt, 1);
                fixlist[f] = row;
            }
        }
    } else {
        // ---- streaming transpose, full-line-per-lane writes ----
        const int bw = blockIdx.x - GATE_BLOCKS;   // 0..2047
        const int w = tid >> 6;
        const int lane = tid & 63;
        const int task = bw * 4 + w;               // 0..8191 = 16 e * 32 kg * 16 ngrp
        const int ngrp = task & 15;
        const int kg   = (task >> 4) & 31;
        const int e    = task >> 9;
        const int n    = ngrp * 64 + lane;
        const float* src = We + ((size_t)e * DK + (size_t)kg * 32) * DN + n;
        float av[32];
        #pragma unroll
        for (int i = 0; i < 32; ++i)
            av[i] = src[(size_t)i * DN];
        u16 pk[32];
        #pragma unroll
        for (int i = 0; i < 32; ++i)
            pk[i] = f2bf(av[i]);
        u16* dst = WeT + ((size_t)e * DN + n) * DK + kg * 32;
        #pragma unroll
        for (int g = 0; g < 4; ++g)
            *(short8*)&dst[g * 8] = *(const short8*)&pk[g * 8];
    }
}

// ---------------- K1b: fp64 exact re-gate of ambiguous rows (block per row) ----------------
__global__ __launch_bounds__(256) void k_fix(const float* __restrict__ x,
                                             const float* __restrict__ Wg,
                                             const float* __restrict__ bg,
                                             const int* __restrict__ fixcnt,
                                             const int* __restrict__ fixlist,
                                             int* __restrict__ cnt,
                                             int* __restrict__ bucket) {
    __shared__ double lred[4][16];
    const int tid = threadIdx.x;
    const int lane = tid & 63;
    const int w = tid >> 6;
    const int n = *fixcnt;
    for (int it = blockIdx.x; it < n; it += 256) {
        const int row = fixlist[it];
        float4 xv = *(const float4*)&x[(size_t)row * DK + tid * 4];
        const float* xf = (const float*)&xv;
        double acc[16];
        #pragma unroll
        for (int e = 0; e < 16; ++e) acc[e] = 0.0;
        #pragma unroll
        for (int j = 0; j < 4; ++j) {
            int k = tid * 4 + j;
            double xd = (double)xf[j];
            const float4* wr = (const float4*)&Wg[(size_t)k * NE];
            float4 w0 = wr[0], w1 = wr[1], w2 = wr[2], w3 = wr[3];
            acc[0]  += xd * (double)w0.x;  acc[1]  += xd * (double)w0.y;
            acc[2]  += xd * (double)w0.z;  acc[3]  += xd * (double)w0.w;
            acc[4]  += xd * (double)w1.x;  acc[5]  += xd * (double)w1.y;
            acc[6]  += xd * (double)w1.z;  acc[7]  += xd * (double)w1.w;
            acc[8]  += xd * (double)w2.x;  acc[9]  += xd * (double)w2.y;
            acc[10] += xd * (double)w2.z;  acc[11] += xd * (double)w2.w;
            acc[12] += xd * (double)w3.x;  acc[13] += xd * (double)w3.y;
            acc[14] += xd * (double)w3.z;  acc[15] += xd * (double)w3.w;
        }
        #pragma unroll
        for (int e = 0; e < 16; ++e) {
            double v = acc[e];
            #pragma unroll
            for (int off = 1; off < 64; off <<= 1)
                v += __shfl_xor(v, off);
            acc[e] = v;
        }
        if (lane == 0) {
            #pragma unroll
            for (int e = 0; e < 16; ++e) lred[w][e] = acc[e];
        }
        __syncthreads();
        if (tid == 0) {
            double best = -1e300; int bi = 0;
            #pragma unroll
            for (int e = 0; e < 16; ++e) {
                double g = lred[0][e] + lred[1][e] + lred[2][e] + lred[3][e]
                         + (double)bg[e];
                if (g > best) { best = g; bi = e; }
            }
            int pos = atomicAdd(&cnt[bi], 1);
            bucket[bi * NB + pos] = row;
        }
        __syncthreads();
    }
}

// ---------------- K3: grouped GEMM, dbuf + COUNTED vmcnt across raw barriers (T3/T4) ----------------
// bf16 MFMA 16x16x32, 128x128 tile, BK=64, 2x(16+16) KB LDS dbuf.
// Per K-step: issue next step's 8 global_load_lds (outstanding<=16), s_waitcnt vmcnt(8)
// (waits only for CURRENT step's 8 - oldest-first), raw s_barrier (no drain), 32 MFMAs,
// raw s_barrier (protects the buffer the next issue overwrites).
// XCD-aware bijective swizzle: nwg=640, 640%8==0 -> 8 n-tiles of a slot share one XCD L2.
__global__ __launch_bounds__(256) void k_moe(const u16* __restrict__ xb,
                                             const u16* __restrict__ WeT,
                                             const float* __restrict__ be,
                                             const int* __restrict__ bucket,
                                             const int* __restrict__ cnt,
                                             float* __restrict__ out) {
    const int bid = blockIdx.x;
    const int swz = (bid & 7) * (MAX_TILES * 8 / 8) + (bid >> 3);
    const int slot = swz >> 3;
    const int nt = swz & 7;

    int e = -1, mt = 0, cntE = 0, acc_t = 0;
    #pragma unroll
    for (int ee = 0; ee < NE; ++ee) {
        int ce = cnt[ee];
        int nte = (ce + TM - 1) / TM;
        if (e < 0 && slot < acc_t + nte) { e = ee; mt = slot - acc_t; cntE = ce; }
        acc_t += nte;
    }
    if (e < 0) return;

    const int m0 = mt * TM;
    const int n0 = nt * TN;

    __shared__ u16 aLds[2][TM * BK];   // 2 x 16 KB
    __shared__ u16 bLds[2][TN * BK];   // 2 x 16 KB

    const int tid = threadIdx.x;
    const int lane = tid & 63;
    const int w = tid >> 6;
    const int wr = w >> 1, wc = w & 1;
    const int lr = lane & 15, q = lane >> 4;

    // staging: chunk c (0..1023) -> row = c>>3, stored slot = c&7, global k16 = slot ^ (row&7)
    long aoff[4]; long boff[4]; int ldsb[4];
    #pragma unroll
    for (int r = 0; r < 4; ++r) {
        int c = r * 256 + tid;
        int row = c >> 3;
        int k16 = (c & 7) ^ (row & 7);
        int m_idx = m0 + row; if (m_idx >= cntE) m_idx = cntE - 1;
        long rid = bucket[e * NB + m_idx];
        aoff[r] = rid * DK + k16 * 8;
        boff[r] = (long)e * DN * DK + (long)(n0 + row) * DK + k16 * 8;
        ldsb[r] = (r * 256 + (tid & ~63)) * 8;   // u16 elems; wave-contiguous 1 KB
    }

    floatx4 acc[4][4];
    #pragma unroll
    for (int mi = 0; mi < 4; ++mi)
        #pragma unroll
        for (int ni = 0; ni < 4; ++ni)
            acc[mi][ni] = (floatx4)0.0f;

    // prologue: stage K-step 0 into buffer 0 (8 loads in flight)
    #pragma unroll
    for (int r = 0; r < 4; ++r)
        gld16(xb + aoff[r], &aLds[0][ldsb[r]]);
    #pragma unroll
    for (int r = 0; r < 4; ++r)
        gld16(WeT + boff[r], &bLds[0][ldsb[r]]);

    int cur = 0;
    #pragma unroll 2
    for (int t = 0; t < DK / BK; ++t) {
        if (t < DK / BK - 1) {
            // issue next K-step into other buffer; its last readers passed the
            // end-of-step barrier of step t-1, so the overwrite is safe.
            const long kk = (long)(t + 1) * BK;
            #pragma unroll
            for (int r = 0; r < 4; ++r)
                gld16(xb + aoff[r] + kk, &aLds[cur ^ 1][ldsb[r]]);
            #pragma unroll
            for (int r = 0; r < 4; ++r)
                gld16(WeT + boff[r] + kk, &bLds[cur ^ 1][ldsb[r]]);
            // wait for step t's 8 oldest loads only; t+1's 8 stay in flight
            asm volatile("s_waitcnt vmcnt(8)" ::: "memory");
        } else {
            asm volatile("s_waitcnt vmcnt(0)" ::: "memory");
        }
        __builtin_amdgcn_s_barrier();   // all waves' step-t loads complete; NO vmcnt(0) drain
        #pragma unroll
        for (int kwin = 0; kwin < 2; ++kwin) {
            const int sl = kwin * 4 + q;    // k16-slot (0..7) for this MFMA window
            short8 af[4], bfr[4];
            #pragma unroll
            for (int mi = 0; mi < 4; ++mi) {
                int row = wr * 64 + mi * 16 + lr;
                af[mi] = *(const short8*)&aLds[cur][row * BK + ((sl ^ (row & 7)) * 8)];
                int nrow = wc * 64 + mi * 16 + lr;
                bfr[mi] = *(const short8*)&bLds[cur][nrow * BK + ((sl ^ (nrow & 7)) * 8)];
            }
            #pragma unroll
            for (int mi = 0; mi < 4; ++mi)
                #pragma unroll
                for (int ni = 0; ni < 4; ++ni)
                    acc[mi][ni] = __builtin_amdgcn_mfma_f32_16x16x32_bf16(
                        af[mi], bfr[ni], acc[mi][ni], 0, 0, 0);
        }
        __builtin_amdgcn_s_barrier();   // buf[cur] fully consumed before next issue overwrites it
        cur ^= 1;
    }

    float bias[4];
    #pragma unroll
    for (int ni = 0; ni < 4; ++ni)
        bias[ni] = be[e * DN + n0 + wc * 64 + ni * 16 + lr];

    #pragma unroll
    for (int mi = 0; mi < 4; ++mi) {
        #pragma unroll
        for (int rr = 0; rr < 4; ++rr) {
            int row_l = wr * 64 + mi * 16 + q * 4 + rr;
            int m_idx = m0 + row_l;
            if (m_idx < cntE) {
                long rid = bucket[e * NB + m_idx];
                float* orow = out + rid * DN + n0 + wc * 64 + lr;
                #pragma unroll
                for (int ni = 0; ni < 4; ++ni)
                    orow[ni * 16] = acc[mi][ni][rr] + bias[ni];
            }
        }
    }
}

extern "C" void kernel_launch(void* const* d_in, const int* in_sizes, int n_in,
                              void* d_out, int out_size, void* d_ws, size_t ws_size,
                              hipStream_t stream) {
    const float* x  = (const float*)d_in[0];
    const float* Wg = (const float*)d_in[1];
    const float* bg = (const float*)d_in[2];
    const float* We = (const float*)d_in[3];
    const float* be = (const float*)d_in[4];
    float* out = (float*)d_out;

    int* cnt     = (int*)d_ws;          // 16 ints
    int* fixcnt  = cnt + 16;            // 1 int
    int* fixlist = cnt + 32;            // up to 8192 ints
    int* bucket  = cnt + 8448;          // 16*8192 ints (ends < 1 MB)
    u16* xb  = (u16*)((char*)d_ws + (1u << 20));    // 16 MB @ 1MB
    u16* wet = (u16*)((char*)d_ws + (18u << 20));   // 32 MB @ 18MB

    hipMemsetAsync(cnt, 0, 20 * sizeof(int), stream);
    k_prep<<<GATE_BLOCKS + TRANS_BLOCKS, 256, 0, stream>>>(x, Wg, bg, We, xb, wet,
                                                           cnt, bucket, fixcnt, fixlist);
    k_fix<<<256, 256, 0, stream>>>(x, Wg, bg, fixcnt, fixlist, cnt, bucket);
    k_moe<<<MAX_TILES * 8, 256, 0, stream>>>(xb, wet, be, bucket, cnt, out);
}

// Round 10
// 210.027 us; speedup vs baseline: 1.0198x; 1.0198x over previous
//
#include <hip/hip_runtime.h>

typedef unsigned short u16;
typedef __attribute__((ext_vector_type(8))) short short8;
typedef __attribute__((ext_vector_type(4))) float floatx4;

#define NB 8192        // rows
#define DK 1024        // D_IN
#define DN 1024        // D_OUT
#define NE 16          // experts
#define TM 128
#define TN 128
#define BK 32
#define MAX_TILES 80   // sum ceil(cnt_e/128) <= 64 + 16
#define GTHR 4e-3f     // split-bf16 gate error < 1e-4 worst-case; 40x margin

#define GATE_BLOCKS 512
#define TRANS_BLOCKS 2048  // 8192 wave-tasks: (e, kgrp of 32, ngrp of 64)

__device__ __forceinline__ u16 f2bf(float f) {
    union { float f; unsigned int u; } v; v.f = f;
    unsigned int u = v.u;
    return (u16)((u + 0x7fffu + ((u >> 16) & 1u)) >> 16);
}

__device__ __forceinline__ float bf2f(u16 h) {
    union { unsigned int u; float f; } v; v.u = ((unsigned int)h) << 16;
    return v.f;
}

__device__ __forceinline__ void gld16(const void* g, void* l) {
    __builtin_amdgcn_global_load_lds(
        (const __attribute__((address_space(1))) unsigned int*)g,
        (__attribute__((address_space(3))) unsigned int*)l, 16, 0, 0);
}

// ---------------- K1: fused [direct-frag split-bf16 MFMA gate + x->bf16] | [streaming We transpose] ----------------
// blocks 0..511: gate, 16 rows each, no staging LDS (frags loaded per-lane from global).
// blocks 512..2559: We fp32 [E][K][N] -> bf16 [E][N][K]; full-64B-line-per-lane writes
//   (no cross-XCD partial-line write amplification).
// Stable at 63.5us across 3 structural variants (R0/R3/R8) - frozen.
__global__ __launch_bounds__(256, 8) void k_prep(const float* __restrict__ x,
                                                 const float* __restrict__ Wg,
                                                 const float* __restrict__ bg,
                                                 const float* __restrict__ We,
                                                 u16* __restrict__ xb,
                                                 u16* __restrict__ WeT,
                                                 int* __restrict__ cnt,
                                                 int* __restrict__ bucket,
                                                 int* __restrict__ fixcnt,
                                                 int* __restrict__ fixlist) {
    __shared__ float gred[4][16 * 17];   // 4.3 KB: cross-wave gate reduction only

    const int tid = threadIdx.x;

    if (blockIdx.x < GATE_BLOCKS) {
        const int lane = tid & 63;
        const int w = tid >> 6;
        const int lr = lane & 15, q = lane >> 4;
        const int R0 = blockIdx.x * 16;
        const size_t xrow = (size_t)(R0 + lr) * DK;

        floatx4 acc = (floatx4)0.0f;

        // wave w covers k in [w*256, w*256+256); per lane: row lr, k-subchunks q*8
        #pragma unroll 2
        for (int cc = 0; cc < 4; ++cc) {
            const int kc = w * 256 + cc * 64;
            #pragma unroll
            for (int kwin = 0; kwin < 2; ++kwin) {
                const int kb = kc + kwin * 32 + q * 8;
                // A fragment: x[R0+lr][kb..kb+8), split hi/lo bf16; emit hi to xb
                const float* gp = &x[xrow + kb];
                float4 v0 = *(const float4*)gp;
                float4 v1 = *(const float4*)(gp + 4);
                float av[8] = { v0.x, v0.y, v0.z, v0.w, v1.x, v1.y, v1.z, v1.w };
                u16 ah[8], al[8];
                #pragma unroll
                for (int j = 0; j < 8; ++j) {
                    ah[j] = f2bf(av[j]);
                    al[j] = f2bf(av[j] - bf2f(ah[j]));
                }
                *(short8*)&xb[xrow + kb] = *(const short8*)ah;
                // B fragment: Wg[kb+j][lr] (col = expert lr), split hi/lo
                float wv[8];
                #pragma unroll
                for (int j = 0; j < 8; ++j)
                    wv[j] = Wg[(size_t)(kb + j) * NE + lr];
                u16 bh[8], bl[8];
                #pragma unroll
                for (int j = 0; j < 8; ++j) {
                    bh[j] = f2bf(wv[j]);
                    bl[j] = f2bf(wv[j] - bf2f(bh[j]));
                }
                const short8 ahv = *(const short8*)ah;
                const short8 alv = *(const short8*)al;
                const short8 bhv = *(const short8*)bh;
                const short8 blv = *(const short8*)bl;
                acc = __builtin_amdgcn_mfma_f32_16x16x32_bf16(ahv, bhv, acc, 0, 0, 0);
                acc = __builtin_amdgcn_mfma_f32_16x16x32_bf16(ahv, blv, acc, 0, 0, 0);
                acc = __builtin_amdgcn_mfma_f32_16x16x32_bf16(alv, bhv, acc, 0, 0, 0);
            }
        }

        #pragma unroll
        for (int rr = 0; rr < 4; ++rr)
            gred[w][(q * 4 + rr) * 17 + lr] = acc[rr];
        __syncthreads();

        if (tid < 16) {
            int row = R0 + tid;
            float g[16];
            #pragma unroll
            for (int e = 0; e < 16; ++e)
                g[e] = gred[0][tid * 17 + e] + gred[1][tid * 17 + e]
                     + gred[2][tid * 17 + e] + gred[3][tid * 17 + e] + bg[e];
            float best = g[0], second = -1e30f; int bi = 0;
            #pragma unroll
            for (int e = 1; e < 16; ++e) {
                if (g[e] > best) { second = best; best = g[e]; bi = e; }
                else if (g[e] > second) second = g[e];
            }
            if (best - second >= GTHR) {
                int pos = atomicAdd(&cnt[bi], 1);
                bucket[bi * NB + pos] = row;
            } else {
                int f = atomicAdd(fixcnt, 1);
                fixlist[f] = row;
            }
        }
    } else {
        // ---- streaming transpose, full-line-per-lane writes ----
        const int bw = blockIdx.x - GATE_BLOCKS;   // 0..2047
        const int w = tid >> 6;
        const int lane = tid & 63;
        const int task = bw * 4 + w;               // 0..8191 = 16 e * 32 kg * 16 ngrp
        const int ngrp = task & 15;
        const int kg   = (task >> 4) & 31;
        const int e    = task >> 9;
        const int n    = ngrp * 64 + lane;
        const float* src = We + ((size_t)e * DK + (size_t)kg * 32) * DN + n;
        float av[32];
        #pragma unroll
        for (int i = 0; i < 32; ++i)
            av[i] = src[(size_t)i * DN];
        u16 pk[32];
        #pragma unroll
        for (int i = 0; i < 32; ++i)
            pk[i] = f2bf(av[i]);
        u16* dst = WeT + ((size_t)e * DN + n) * DK + kg * 32;
        #pragma unroll
        for (int g = 0; g < 4; ++g)
            *(short8*)&dst[g * 8] = *(const short8*)&pk[g * 8];
    }
}

// ---------------- K1b: fp64 exact re-gate of ambiguous rows (block per row) ----------------
__global__ __launch_bounds__(256) void k_fix(const float* __restrict__ x,
                                             const float* __restrict__ Wg,
                                             const float* __restrict__ bg,
                                             const int* __restrict__ fixcnt,
                                             const int* __restrict__ fixlist,
                                             int* __restrict__ cnt,
                                             int* __restrict__ bucket) {
    __shared__ double lred[4][16];
    const int tid = threadIdx.x;
    const int lane = tid & 63;
    const int w = tid >> 6;
    const int n = *fixcnt;
    for (int it = blockIdx.x; it < n; it += 256) {
        const int row = fixlist[it];
        float4 xv = *(const float4*)&x[(size_t)row * DK + tid * 4];
        const float* xf = (const float*)&xv;
        double acc[16];
        #pragma unroll
        for (int e = 0; e < 16; ++e) acc[e] = 0.0;
        #pragma unroll
        for (int j = 0; j < 4; ++j) {
            int k = tid * 4 + j;
            double xd = (double)xf[j];
            const float4* wr = (const float4*)&Wg[(size_t)k * NE];
            float4 w0 = wr[0], w1 = wr[1], w2 = wr[2], w3 = wr[3];
            acc[0]  += xd * (double)w0.x;  acc[1]  += xd * (double)w0.y;
            acc[2]  += xd * (double)w0.z;  acc[3]  += xd * (double)w0.w;
            acc[4]  += xd * (double)w1.x;  acc[5]  += xd * (double)w1.y;
            acc[6]  += xd * (double)w1.z;  acc[7]  += xd * (double)w1.w;
            acc[8]  += xd * (double)w2.x;  acc[9]  += xd * (double)w2.y;
            acc[10] += xd * (double)w2.z;  acc[11] += xd * (double)w2.w;
            acc[12] += xd * (double)w3.x;  acc[13] += xd * (double)w3.y;
            acc[14] += xd * (double)w3.z;  acc[15] += xd * (double)w3.w;
        }
        #pragma unroll
        for (int e = 0; e < 16; ++e) {
            double v = acc[e];
            #pragma unroll
            for (int off = 1; off < 64; off <<= 1)
                v += __shfl_xor(v, off);
            acc[e] = v;
        }
        if (lane == 0) {
            #pragma unroll
            for (int e = 0; e < 16; ++e) lred[w][e] = acc[e];
        }
        __syncthreads();
        if (tid == 0) {
            double best = -1e300; int bi = 0;
            #pragma unroll
            for (int e = 0; e < 16; ++e) {
                double g = lred[0][e] + lred[1][e] + lred[2][e] + lred[3][e]
                         + (double)bg[e];
                if (g > best) { best = g; bi = e; }
            }
            int pos = atomicAdd(&cnt[bi], 1);
            bucket[bi * NB + pos] = row;
        }
        __syncthreads();
    }
}

// ---------------- K3: grouped GEMM, BK=32 dbuf + counted vmcnt (4 blocks/CU, zero tail) ----------------
// bf16 MFMA 16x16x32, 128x128 tile, BK=32, 2x(8+8) KB LDS dbuf = 32 KB -> 4 blocks/CU;
// grid 640 blocks < 1024 resident slots -> ALL blocks co-resident, no tail round.
// Per K-step: issue next step's 4 global_load_lds, s_waitcnt vmcnt(4) (waits current
// step's 4, oldest-first), raw s_barrier, 16 MFMAs, raw s_barrier.
// LDS swizzle: chunk c -> row=c>>2, stored slot=c&3, global k16 = slot^(row&3)^((row>>2)&3).
//   Read at row*32+((q^(row&3)^((row>>2)&3))*8) recovers k16=q. Bank check: row stride
//   64B = half the banks; within a parity class the 8 rows' xor keys cycle all 4 slot
//   values twice -> 2 lanes/bank-set = free (m136).
// XCD-aware bijective swizzle: nwg=640, 640%8==0.
__global__ __launch_bounds__(256) void k_moe(const u16* __restrict__ xb,
                                             const u16* __restrict__ WeT,
                                             const float* __restrict__ be,
                                             const int* __restrict__ bucket,
                                             const int* __restrict__ cnt,
                                             float* __restrict__ out) {
    const int bid = blockIdx.x;
    const int swz = (bid & 7) * (MAX_TILES * 8 / 8) + (bid >> 3);
    const int slot = swz >> 3;
    const int nt = swz & 7;

    int e = -1, mt = 0, cntE = 0, acc_t = 0;
    #pragma unroll
    for (int ee = 0; ee < NE; ++ee) {
        int ce = cnt[ee];
        int nte = (ce + TM - 1) / TM;
        if (e < 0 && slot < acc_t + nte) { e = ee; mt = slot - acc_t; cntE = ce; }
        acc_t += nte;
    }
    if (e < 0) return;

    const int m0 = mt * TM;
    const int n0 = nt * TN;

    __shared__ u16 aLds[2][TM * BK];   // 2 x 8 KB
    __shared__ u16 bLds[2][TN * BK];   // 2 x 8 KB

    const int tid = threadIdx.x;
    const int lane = tid & 63;
    const int w = tid >> 6;
    const int wr = w >> 1, wc = w & 1;
    const int lr = lane & 15, q = lane >> 4;

    // staging: chunk c (0..511) -> row = c>>2, stored slot = c&3,
    // global k16 = (c&3) ^ (row&3) ^ ((row>>2)&3)
    long aoff[2]; long boff[2]; int ldsb[2];
    #pragma unroll
    for (int r = 0; r < 2; ++r) {
        int c = r * 256 + tid;
        int row = c >> 2;
        int k16 = (c & 3) ^ (row & 3) ^ ((row >> 2) & 3);
        int m_idx = m0 + row; if (m_idx >= cntE) m_idx = cntE - 1;
        long rid = bucket[e * NB + m_idx];
        aoff[r] = rid * DK + k16 * 8;
        boff[r] = (long)e * DN * DK + (long)(n0 + row) * DK + k16 * 8;
        ldsb[r] = (r * 256 + (tid & ~63)) * 8;   // u16 elems; wave-contiguous 1 KB
    }

    floatx4 acc[4][4];
    #pragma unroll
    for (int mi = 0; mi < 4; ++mi)
        #pragma unroll
        for (int ni = 0; ni < 4; ++ni)
            acc[mi][ni] = (floatx4)0.0f;

    // prologue: stage K-step 0 into buffer 0 (4 loads in flight)
    #pragma unroll
    for (int r = 0; r < 2; ++r)
        gld16(xb + aoff[r], &aLds[0][ldsb[r]]);
    #pragma unroll
    for (int r = 0; r < 2; ++r)
        gld16(WeT + boff[r], &bLds[0][ldsb[r]]);

    int cur = 0;
    #pragma unroll 2
    for (int t = 0; t < DK / BK; ++t) {
        if (t < DK / BK - 1) {
            // issue next K-step into other buffer; its last readers passed the
            // end-of-step barrier of step t-1, so the overwrite is safe.
            const long kk = (long)(t + 1) * BK;
            #pragma unroll
            for (int r = 0; r < 2; ++r)
                gld16(xb + aoff[r] + kk, &aLds[cur ^ 1][ldsb[r]]);
            #pragma unroll
            for (int r = 0; r < 2; ++r)
                gld16(WeT + boff[r] + kk, &bLds[cur ^ 1][ldsb[r]]);
            // wait for step t's 4 oldest loads only; t+1's 4 stay in flight
            asm volatile("s_waitcnt vmcnt(4)" ::: "memory");
        } else {
            asm volatile("s_waitcnt vmcnt(0)" ::: "memory");
        }
        __builtin_amdgcn_s_barrier();   // all waves' step-t loads complete; no drain
        {
            short8 af[4], bfr[4];
            #pragma unroll
            for (int mi = 0; mi < 4; ++mi) {
                int row = wr * 64 + mi * 16 + lr;
                af[mi] = *(const short8*)&aLds[cur][row * BK
                        + ((q ^ (row & 3) ^ ((row >> 2) & 3)) * 8)];
                int nrow = wc * 64 + mi * 16 + lr;
                bfr[mi] = *(const short8*)&bLds[cur][nrow * BK
                        + ((q ^ (nrow & 3) ^ ((nrow >> 2) & 3)) * 8)];
            }
            #pragma unroll
            for (int mi = 0; mi < 4; ++mi)
                #pragma unroll
                for (int ni = 0; ni < 4; ++ni)
                    acc[mi][ni] = __builtin_amdgcn_mfma_f32_16x16x32_bf16(
                        af[mi], bfr[ni], acc[mi][ni], 0, 0, 0);
        }
        __builtin_amdgcn_s_barrier();   // buf[cur] fully consumed before next issue overwrites it
        cur ^= 1;
    }

    float bias[4];
    #pragma unroll
    for (int ni = 0; ni < 4; ++ni)
        bias[ni] = be[e * DN + n0 + wc * 64 + ni * 16 + lr];

    #pragma unroll
    for (int mi = 0; mi < 4; ++mi) {
        #pragma unroll
        for (int rr = 0; rr < 4; ++rr) {
            int row_l = wr * 64 + mi * 16 + q * 4 + rr;
            int m_idx = m0 + row_l;
            if (m_idx < cntE) {
                long rid = bucket[e * NB + m_idx];
                float* orow = out + rid * DN + n0 + wc * 64 + lr;
                #pragma unroll
                for (int ni = 0; ni < 4; ++ni)
                    orow[ni * 16] = acc[mi][ni][rr] + bias[ni];
            }
        }
    }
}

extern "C" void kernel_launch(void* const* d_in, const int* in_sizes, int n_in,
                              void* d_out, int out_size, void* d_ws, size_t ws_size,
                              hipStream_t stream) {
    const float* x  = (const float*)d_in[0];
    const float* Wg = (const float*)d_in[1];
    const float* bg = (const float*)d_in[2];
    const float* We = (const float*)d_in[3];
    const float* be = (const float*)d_in[4];
    float* out = (float*)d_out;

    int* cnt     = (int*)d_ws;          // 16 ints
    int* fixcnt  = cnt + 16;            // 1 int
    int* fixlist = cnt + 32;            // up to 8192 ints
    int* bucket  = cnt + 8448;          // 16*8192 ints (ends < 1 MB)
    u16* xb  = (u16*)((char*)d_ws + (1u << 20));    // 16 MB @ 1MB
    u16* wet = (u16*)((char*)d_ws + (18u << 20));   // 32 MB @ 18MB

    hipMemsetAsync(cnt, 0, 20 * sizeof(int), stream);
    k_prep<<<GATE_BLOCKS + TRANS_BLOCKS, 256, 0, stream>>>(x, Wg, bg, We, xb, wet,
                                                           cnt, bucket, fixcnt, fixlist);
    k_fix<<<256, 256, 0, stream>>>(x, Wg, bg, fixcnt, fixlist, cnt, bucket);
    k_moe<<<MAX_TILES * 8, 256, 0, stream>>>(xb, wet, be, bucket, cnt, out);
}

// Round 11
// 207.808 us; speedup vs baseline: 1.0307x; 1.0107x over previous
//
#include <hip/hip_runtime.h>

typedef unsigned short u16;
typedef __attribute__((ext_vector_type(8))) short short8;
typedef __attribute__((ext_vector_type(4))) float floatx4;

#define NB 8192        // rows
#define DK 1024        // D_IN
#define DN 1024        // D_OUT
#define NE 16          // experts
#define TM 128
#define TN 128
#define BK 32
#define MAX_TILES 80   // sum ceil(cnt_e/128) <= 64 + 16
#define GTHR 4e-3f     // split-bf16 gate error < 1e-4 worst-case; 40x margin

#define GATE_BLOCKS 512
#define TRANS_BLOCKS 2048  // 8192 wave-tasks: (e, kgrp of 32, ngrp of 64)

__device__ __forceinline__ u16 f2bf(float f) {
    union { float f; unsigned int u; } v; v.f = f;
    unsigned int u = v.u;
    return (u16)((u + 0x7fffu + ((u >> 16) & 1u)) >> 16);
}

__device__ __forceinline__ float bf2f(u16 h) {
    union { unsigned int u; float f; } v; v.u = ((unsigned int)h) << 16;
    return v.f;
}

__device__ __forceinline__ void gld16(const void* g, void* l) {
    __builtin_amdgcn_global_load_lds(
        (const __attribute__((address_space(1))) unsigned int*)g,
        (__attribute__((address_space(3))) unsigned int*)l, 16, 0, 0);
}

// ---------------- K1: fused [direct-frag split-bf16 MFMA gate + x->bf16] | [streaming We transpose] ----------------
// blocks 0..511: gate, 16 rows each, no staging LDS (frags loaded per-lane from global).
// blocks 512..2559: We fp32 [E][K][N] -> bf16 [E][N][K]; full-64B-line-per-lane writes
//   (no cross-XCD partial-line write amplification).
// Stable at 63.5us across 3 structural variants (R0/R3/R8) - frozen.
__global__ __launch_bounds__(256, 8) void k_prep(const float* __restrict__ x,
                                                 const float* __restrict__ Wg,
                                                 const float* __restrict__ bg,
                                                 const float* __restrict__ We,
                                                 u16* __restrict__ xb,
                                                 u16* __restrict__ WeT,
                                                 int* __restrict__ cnt,
                                                 int* __restrict__ bucket,
                                                 int* __restrict__ fixcnt,
                                                 int* __restrict__ fixlist) {
    __shared__ float gred[4][16 * 17];   // 4.3 KB: cross-wave gate reduction only

    const int tid = threadIdx.x;

    if (blockIdx.x < GATE_BLOCKS) {
        const int lane = tid & 63;
        const int w = tid >> 6;
        const int lr = lane & 15, q = lane >> 4;
        const int R0 = blockIdx.x * 16;
        const size_t xrow = (size_t)(R0 + lr) * DK;

        floatx4 acc = (floatx4)0.0f;

        // wave w covers k in [w*256, w*256+256); per lane: row lr, k-subchunks q*8
        #pragma unroll 2
        for (int cc = 0; cc < 4; ++cc) {
            const int kc = w * 256 + cc * 64;
            #pragma unroll
            for (int kwin = 0; kwin < 2; ++kwin) {
                const int kb = kc + kwin * 32 + q * 8;
                // A fragment: x[R0+lr][kb..kb+8), split hi/lo bf16; emit hi to xb
                const float* gp = &x[xrow + kb];
                float4 v0 = *(const float4*)gp;
                float4 v1 = *(const float4*)(gp + 4);
                float av[8] = { v0.x, v0.y, v0.z, v0.w, v1.x, v1.y, v1.z, v1.w };
                u16 ah[8], al[8];
                #pragma unroll
                for (int j = 0; j < 8; ++j) {
                    ah[j] = f2bf(av[j]);
                    al[j] = f2bf(av[j] - bf2f(ah[j]));
                }
                *(short8*)&xb[xrow + kb] = *(const short8*)ah;
                // B fragment: Wg[kb+j][lr] (col = expert lr), split hi/lo
                float wv[8];
                #pragma unroll
                for (int j = 0; j < 8; ++j)
                    wv[j] = Wg[(size_t)(kb + j) * NE + lr];
                u16 bh[8], bl[8];
                #pragma unroll
                for (int j = 0; j < 8; ++j) {
                    bh[j] = f2bf(wv[j]);
                    bl[j] = f2bf(wv[j] - bf2f(bh[j]));
                }
                const short8 ahv = *(const short8*)ah;
                const short8 alv = *(const short8*)al;
                const short8 bhv = *(const short8*)bh;
                const short8 blv = *(const short8*)bl;
                acc = __builtin_amdgcn_mfma_f32_16x16x32_bf16(ahv, bhv, acc, 0, 0, 0);
                acc = __builtin_amdgcn_mfma_f32_16x16x32_bf16(ahv, blv, acc, 0, 0, 0);
                acc = __builtin_amdgcn_mfma_f32_16x16x32_bf16(alv, bhv, acc, 0, 0, 0);
            }
        }

        #pragma unroll
        for (int rr = 0; rr < 4; ++rr)
            gred[w][(q * 4 + rr) * 17 + lr] = acc[rr];
        __syncthreads();

        if (tid < 16) {
            int row = R0 + tid;
            float g[16];
            #pragma unroll
            for (int e = 0; e < 16; ++e)
                g[e] = gred[0][tid * 17 + e] + gred[1][tid * 17 + e]
                     + gred[2][tid * 17 + e] + gred[3][tid * 17 + e] + bg[e];
            float best = g[0], second = -1e30f; int bi = 0;
            #pragma unroll
            for (int e = 1; e < 16; ++e) {
                if (g[e] > best) { second = best; best = g[e]; bi = e; }
                else if (g[e] > second) second = g[e];
            }
            if (best - second >= GTHR) {
                int pos = atomicAdd(&cnt[bi], 1);
                bucket[bi * NB + pos] = row;
            } else {
                int f = atomicAdd(fixcnt, 1);
                fixlist[f] = row;
            }
        }
    } else {
        // ---- streaming transpose, full-line-per-lane writes ----
        const int bw = blockIdx.x - GATE_BLOCKS;   // 0..2047
        const int w = tid >> 6;
        const int lane = tid & 63;
        const int task = bw * 4 + w;               // 0..8191 = 16 e * 32 kg * 16 ngrp
        const int ngrp = task & 15;
        const int kg   = (task >> 4) & 31;
        const int e    = task >> 9;
        const int n    = ngrp * 64 + lane;
        const float* src = We + ((size_t)e * DK + (size_t)kg * 32) * DN + n;
        float av[32];
        #pragma unroll
        for (int i = 0; i < 32; ++i)
            av[i] = src[(size_t)i * DN];
        u16 pk[32];
        #pragma unroll
        for (int i = 0; i < 32; ++i)
            pk[i] = f2bf(av[i]);
        u16* dst = WeT + ((size_t)e * DN + n) * DK + kg * 32;
        #pragma unroll
        for (int g = 0; g < 4; ++g)
            *(short8*)&dst[g * 8] = *(const short8*)&pk[g * 8];
    }
}

// ---------------- K1b: fp64 exact re-gate of ambiguous rows (block per row) ----------------
__global__ __launch_bounds__(256) void k_fix(const float* __restrict__ x,
                                             const float* __restrict__ Wg,
                                             const float* __restrict__ bg,
                                             const int* __restrict__ fixcnt,
                                             const int* __restrict__ fixlist,
                                             int* __restrict__ cnt,
                                             int* __restrict__ bucket) {
    __shared__ double lred[4][16];
    const int tid = threadIdx.x;
    const int lane = tid & 63;
    const int w = tid >> 6;
    const int n = *fixcnt;
    for (int it = blockIdx.x; it < n; it += 256) {
        const int row = fixlist[it];
        float4 xv = *(const float4*)&x[(size_t)row * DK + tid * 4];
        const float* xf = (const float*)&xv;
        double acc[16];
        #pragma unroll
        for (int e = 0; e < 16; ++e) acc[e] = 0.0;
        #pragma unroll
        for (int j = 0; j < 4; ++j) {
            int k = tid * 4 + j;
            double xd = (double)xf[j];
            const float4* wr = (const float4*)&Wg[(size_t)k * NE];
            float4 w0 = wr[0], w1 = wr[1], w2 = wr[2], w3 = wr[3];
            acc[0]  += xd * (double)w0.x;  acc[1]  += xd * (double)w0.y;
            acc[2]  += xd * (double)w0.z;  acc[3]  += xd * (double)w0.w;
            acc[4]  += xd * (double)w1.x;  acc[5]  += xd * (double)w1.y;
            acc[6]  += xd * (double)w1.z;  acc[7]  += xd * (double)w1.w;
            acc[8]  += xd * (double)w2.x;  acc[9]  += xd * (double)w2.y;
            acc[10] += xd * (double)w2.z;  acc[11] += xd * (double)w2.w;
            acc[12] += xd * (double)w3.x;  acc[13] += xd * (double)w3.y;
            acc[14] += xd * (double)w3.z;  acc[15] += xd * (double)w3.w;
        }
        #pragma unroll
        for (int e = 0; e < 16; ++e) {
            double v = acc[e];
            #pragma unroll
            for (int off = 1; off < 64; off <<= 1)
                v += __shfl_xor(v, off);
            acc[e] = v;
        }
        if (lane == 0) {
            #pragma unroll
            for (int e = 0; e < 16; ++e) lred[w][e] = acc[e];
        }
        __syncthreads();
        if (tid == 0) {
            double best = -1e300; int bi = 0;
            #pragma unroll
            for (int e = 0; e < 16; ++e) {
                double g = lred[0][e] + lred[1][e] + lred[2][e] + lred[3][e]
                         + (double)bg[e];
                if (g > best) { best = g; bi = e; }
            }
            int pos = atomicAdd(&cnt[bi], 1);
            bucket[bi * NB + pos] = row;
        }
        __syncthreads();
    }
}

// ---------------- K3: grouped GEMM, BK=32 dbuf + counted vmcnt + T5 setprio ----------------
// bf16 MFMA 16x16x32, 128x128 tile, BK=32, 2x(8+8) KB LDS dbuf = 32 KB -> 4 blocks/CU,
// all 640 blocks co-resident, zero tail. Per K-step: issue next step's 4 global_load_lds,
// s_waitcnt vmcnt(4), raw s_barrier, setprio(1) + 16 MFMAs + setprio(0), raw s_barrier.
// T5: on counted-vmcnt phase-split schedules with wave role diversity, setprio around
// the MFMA cluster measured +21-39% (m218b/m224); null only on lockstep schedules (m190).
// LDS swizzle: chunk c -> row=c>>2, slot=c&3, global k16 = slot^(row&3)^((row>>2)&3).
// XCD-aware bijective swizzle: nwg=640, 640%8==0.
__global__ __launch_bounds__(256) void k_moe(const u16* __restrict__ xb,
                                             const u16* __restrict__ WeT,
                                             const float* __restrict__ be,
                                             const int* __restrict__ bucket,
                                             const int* __restrict__ cnt,
                                             float* __restrict__ out) {
    const int bid = blockIdx.x;
    const int swz = (bid & 7) * (MAX_TILES * 8 / 8) + (bid >> 3);
    const int slot = swz >> 3;
    const int nt = swz & 7;

    int e = -1, mt = 0, cntE = 0, acc_t = 0;
    #pragma unroll
    for (int ee = 0; ee < NE; ++ee) {
        int ce = cnt[ee];
        int nte = (ce + TM - 1) / TM;
        if (e < 0 && slot < acc_t + nte) { e = ee; mt = slot - acc_t; cntE = ce; }
        acc_t += nte;
    }
    if (e < 0) return;

    const int m0 = mt * TM;
    const int n0 = nt * TN;

    __shared__ u16 aLds[2][TM * BK];   // 2 x 8 KB
    __shared__ u16 bLds[2][TN * BK];   // 2 x 8 KB

    const int tid = threadIdx.x;
    const int lane = tid & 63;
    const int w = tid >> 6;
    const int wr = w >> 1, wc = w & 1;
    const int lr = lane & 15, q = lane >> 4;

    // staging: chunk c (0..511) -> row = c>>2, stored slot = c&3,
    // global k16 = (c&3) ^ (row&3) ^ ((row>>2)&3)
    long aoff[2]; long boff[2]; int ldsb[2];
    #pragma unroll
    for (int r = 0; r < 2; ++r) {
        int c = r * 256 + tid;
        int row = c >> 2;
        int k16 = (c & 3) ^ (row & 3) ^ ((row >> 2) & 3);
        int m_idx = m0 + row; if (m_idx >= cntE) m_idx = cntE - 1;
        long rid = bucket[e * NB + m_idx];
        aoff[r] = rid * DK + k16 * 8;
        boff[r] = (long)e * DN * DK + (long)(n0 + row) * DK + k16 * 8;
        ldsb[r] = (r * 256 + (tid & ~63)) * 8;   // u16 elems; wave-contiguous 1 KB
    }

    floatx4 acc[4][4];
    #pragma unroll
    for (int mi = 0; mi < 4; ++mi)
        #pragma unroll
        for (int ni = 0; ni < 4; ++ni)
            acc[mi][ni] = (floatx4)0.0f;

    // prologue: stage K-step 0 into buffer 0 (4 loads in flight)
    #pragma unroll
    for (int r = 0; r < 2; ++r)
        gld16(xb + aoff[r], &aLds[0][ldsb[r]]);
    #pragma unroll
    for (int r = 0; r < 2; ++r)
        gld16(WeT + boff[r], &bLds[0][ldsb[r]]);

    int cur = 0;
    #pragma unroll 2
    for (int t = 0; t < DK / BK; ++t) {
        if (t < DK / BK - 1) {
            // issue next K-step into other buffer; its last readers passed the
            // end-of-step barrier of step t-1, so the overwrite is safe.
            const long kk = (long)(t + 1) * BK;
            #pragma unroll
            for (int r = 0; r < 2; ++r)
                gld16(xb + aoff[r] + kk, &aLds[cur ^ 1][ldsb[r]]);
            #pragma unroll
            for (int r = 0; r < 2; ++r)
                gld16(WeT + boff[r] + kk, &bLds[cur ^ 1][ldsb[r]]);
            // wait for step t's 4 oldest loads only; t+1's 4 stay in flight
            asm volatile("s_waitcnt vmcnt(4)" ::: "memory");
        } else {
            asm volatile("s_waitcnt vmcnt(0)" ::: "memory");
        }
        __builtin_amdgcn_s_barrier();   // all waves' step-t loads complete; no drain
        {
            short8 af[4], bfr[4];
            #pragma unroll
            for (int mi = 0; mi < 4; ++mi) {
                int row = wr * 64 + mi * 16 + lr;
                af[mi] = *(const short8*)&aLds[cur][row * BK
                        + ((q ^ (row & 3) ^ ((row >> 2) & 3)) * 8)];
                int nrow = wc * 64 + mi * 16 + lr;
                bfr[mi] = *(const short8*)&bLds[cur][nrow * BK
                        + ((q ^ (nrow & 3) ^ ((nrow >> 2) & 3)) * 8)];
            }
            __builtin_amdgcn_s_setprio(1);
            #pragma unroll
            for (int mi = 0; mi < 4; ++mi)
                #pragma unroll
                for (int ni = 0; ni < 4; ++ni)
                    acc[mi][ni] = __builtin_amdgcn_mfma_f32_16x16x32_bf16(
                        af[mi], bfr[ni], acc[mi][ni], 0, 0, 0);
            __builtin_amdgcn_s_setprio(0);
        }
        __builtin_amdgcn_s_barrier();   // buf[cur] fully consumed before next issue overwrites it
        cur ^= 1;
    }

    float bias[4];
    #pragma unroll
    for (int ni = 0; ni < 4; ++ni)
        bias[ni] = be[e * DN + n0 + wc * 64 + ni * 16 + lr];

    #pragma unroll
    for (int mi = 0; mi < 4; ++mi) {
        #pragma unroll
        for (int rr = 0; rr < 4; ++rr) {
            int row_l = wr * 64 + mi * 16 + q * 4 + rr;
            int m_idx = m0 + row_l;
            if (m_idx < cntE) {
                long rid = bucket[e * NB + m_idx];
                float* orow = out + rid * DN + n0 + wc * 64 + lr;
                #pragma unroll
                for (int ni = 0; ni < 4; ++ni)
                    orow[ni * 16] = acc[mi][ni][rr] + bias[ni];
            }
        }
    }
}

extern "C" void kernel_launch(void* const* d_in, const int* in_sizes, int n_in,
                              void* d_out, int out_size, void* d_ws, size_t ws_size,
                              hipStream_t stream) {
    const float* x  = (const float*)d_in[0];
    const float* Wg = (const float*)d_in[1];
    const float* bg = (const float*)d_in[2];
    const float* We = (const float*)d_in[3];
    const float* be = (const float*)d_in[4];
    float* out = (float*)d_out;

    int* cnt     = (int*)d_ws;          // 16 ints
    int* fixcnt  = cnt + 16;            // 1 int
    int* fixlist = cnt + 32;            // up to 8192 ints
    int* bucket  = cnt + 8448;          // 16*8192 ints (ends < 1 MB)
    u16* xb  = (u16*)((char*)d_ws + (1u << 20));    // 16 MB @ 1MB
    u16* wet = (u16*)((char*)d_ws + (18u << 20));   // 32 MB @ 18MB

    hipMemsetAsync(cnt, 0, 20 * sizeof(int), stream);
    k_prep<<<GATE_BLOCKS + TRANS_BLOCKS, 256, 0, stream>>>(x, Wg, bg, We, xb, wet,
                                                           cnt, bucket, fixcnt, fixlist);
    k_fix<<<256, 256, 0, stream>>>(x, Wg, bg, fixcnt, fixlist, cnt, bucket);
    k_moe<<<MAX_TILES * 8, 256, 0, stream>>>(xb, wet, be, bucket, cnt, out);
}